// Round 3
// baseline (765.318 us; speedup 1.0000x reference)
//
#include <hip/hip_runtime.h>
#include <math.h>

#define N 8192
#define F 8
#define RPW 2                 // rows per wave
#define WPB 4                 // waves per block
#define RPB (RPW * WPB)       // 8 rows per block
#define JSPLIT 4
#define JCHUNK (N / JSPLIT)   // 2048 columns per block
#define TJ 256                // j-tile staged in LDS per iteration
#define NIT (JCHUNK / TJ)     // 8 iterations
#define THRF 0.9f

// msg[i][f] = sum_j max(A[i][j], fid_adj[i][j]) * X[j][f]
// fid_adj = 1 iff (xn_i . xn_j)^2 >= 0.9 and i != j, xn = X/(||X||+1e-12).
// A ~ U[0,1) so max(a,1)==1 exactly -> adj = sel ? 1.0f : a.
//
// v4 (from v3):
//  - RPW 4->2: per-wave state ~halved (acc 16, A-prefetch 2x8, stage 8)
//    -> target ~70 VGPR, 6+ waves/SIMD for latency hiding (v3 was the
//    remaining bottleneck: VALUBusy ~29%, both pipes idle).
//  - A loads back to float4 (1KB/wave-inst, 4x fewer than v3's dwords).
//    Row-swizzle applied on the STAGE-side global address
//    (slot k*64+lane holds tile-row lane*4+k) so compute reads stay
//    stride-1 f-major: bank-conflict-free reads AND linear writes.
//  - atomics+memset removed: plain stores to per-JSPLIT partial buffers
//    (every element written exactly once -> workspace poison safe);
//    mlp sums the 4 partials.
//  - select test on raw X: (xi.X_j)^2 >= 0.9*||X_j||^2; diagonal handled
//    post-reduction: v += (A[i][i]-1)*X[i][f]  (verified in v3).
__global__ __launch_bounds__(256, 6) void msg_pass_kernel(
    const float* __restrict__ A, const float* __restrict__ X,
    float* __restrict__ msgp) {
  __shared__ float xT[2][F][TJ];  // raw X tile, f-major, row-swizzled
  __shared__ float tq[2][TJ];     // 0.9 * ||X_row||^2, same swizzle

  const int t = threadIdx.x;
  const int lane = t & 63;
  const int wave = t >> 6;
  const int i0 = blockIdx.x * RPB + wave * RPW;
  const int jbase = blockIdx.y * JCHUNK;

  // Normalized xi rows (wave-uniform) hoisted to SGPRs.
  float xi[RPW][F];
#pragma unroll
  for (int r = 0; r < RPW; ++r) {
    const float4* xp = (const float4*)(X + (size_t)(i0 + r) * F);
    const float4 lo = xp[0], hi = xp[1];
    const float ss = lo.x * lo.x + lo.y * lo.y + lo.z * lo.z + lo.w * lo.w +
                     hi.x * hi.x + hi.y * hi.y + hi.z * hi.z + hi.w * hi.w;
    const float inv = 1.0f / (sqrtf(ss) + 1e-12f);
    const float v[F] = {lo.x * inv, lo.y * inv, lo.z * inv, lo.w * inv,
                        hi.x * inv, hi.y * inv, hi.z * inv, hi.w * inv};
#pragma unroll
    for (int f = 0; f < F; ++f)
      xi[r][f] = __int_as_float(
          __builtin_amdgcn_readfirstlane(__float_as_int(v[f])));
  }

  float acc[RPW][F];
#pragma unroll
  for (int r = 0; r < RPW; ++r)
#pragma unroll
    for (int f = 0; f < F; ++f) acc[r][f] = 0.f;

  // Stage-side source row for thread t: slot t holds tile-row
  // (t&63)*4 + (t>>6)  (so compute slot k*64+lane == tile-row lane*4+k).
  const int srow = (lane << 2) | wave;

  auto loadA = [&](float4 av[RPW], int it) {
    const size_t col = (size_t)jbase + (size_t)it * TJ + (size_t)lane * 4;
#pragma unroll
    for (int r = 0; r < RPW; ++r)
      av[r] = *(const float4*)(A + (size_t)(i0 + r) * N + col);
  };
  auto loadX = [&](float4& lo, float4& hi, int it) {
    const float4* xp =
        (const float4*)(X + (size_t)(jbase + it * TJ + srow) * F);
    lo = xp[0];
    hi = xp[1];
  };
  auto stage = [&](int b, const float4& lo, const float4& hi) {
    const float ss = lo.x * lo.x + lo.y * lo.y + lo.z * lo.z + lo.w * lo.w +
                     hi.x * hi.x + hi.y * hi.y + hi.z * hi.z + hi.w * hi.w;
    xT[b][0][t] = lo.x; xT[b][1][t] = lo.y;
    xT[b][2][t] = lo.z; xT[b][3][t] = lo.w;
    xT[b][4][t] = hi.x; xT[b][5][t] = hi.y;
    xT[b][6][t] = hi.z; xT[b][7][t] = hi.w;
    tq[b][t] = THRF * ss;
  };
  auto compute = [&](int b, const float4 av[RPW]) {
#pragma unroll
    for (int k = 0; k < 4; ++k) {
      const int slot = k * 64 + lane;
      float xj[F];
#pragma unroll
      for (int f = 0; f < F; ++f) xj[f] = xT[b][f][slot];
      const float tj = tq[b][slot];
#pragma unroll
      for (int r = 0; r < RPW; ++r) {
        float dot = 0.f;
#pragma unroll
        for (int f = 0; f < F; ++f) dot = fmaf(xi[r][f], xj[f], dot);
        const float a = (k == 0)   ? av[r].x
                        : (k == 1) ? av[r].y
                        : (k == 2) ? av[r].z
                                   : av[r].w;
        const float c = (dot * dot >= tj) ? 1.0f : a;
#pragma unroll
        for (int f = 0; f < F; ++f) acc[r][f] = fmaf(c, xj[f], acc[r][f]);
      }
    }
  };

  // Prologue: tile 0 resident in buf0 + av0.
  float4 av0[RPW], av1[RPW];
  float4 plo, phi;
  loadA(av0, 0);
  loadX(plo, phi, 0);
  stage(0, plo, phi);
  __syncthreads();

#pragma unroll 1
  for (int ith = 0; ith < NIT; ith += 2) {
    loadA(av1, ith + 1);
    loadX(plo, phi, ith + 1);
    compute(0, av0);
    stage(1, plo, phi);
    __syncthreads();
    if (ith + 2 < NIT) {
      loadA(av0, ith + 2);
      loadX(plo, phi, ith + 2);
    }
    compute(1, av1);
    if (ith + 2 < NIT) stage(0, plo, phi);
    __syncthreads();
  }

  // Butterfly reduce; lane (r*8+f) owns that output. Diagonal term (added
  // with coef 1.0 in-loop) repaired here: += (A[i][i]-1)*X[i][f].
  const bool diagblk = ((unsigned)(i0 - jbase) < (unsigned)JCHUNK);
#pragma unroll
  for (int r = 0; r < RPW; ++r) {
#pragma unroll
    for (int f = 0; f < F; ++f) {
      float v = acc[r][f];
#pragma unroll
      for (int off = 1; off < 64; off <<= 1) v += __shfl_xor(v, off, 64);
      if (lane == r * F + f) {
        if (diagblk) {
          const int i = i0 + r;
          v += (A[(size_t)i * N + i] - 1.0f) * X[(size_t)i * F + f];
        }
        msgp[((size_t)blockIdx.y * N + (i0 + r)) * F + f] = v;
      }
    }
  }
}

__device__ __forceinline__ float sigmoidf_(float z) {
  return 1.0f / (1.0f + expf(-z));
}

// Per-node MLP chain. Weights are (fan_in, fan_out) row-major.
// h0 = sum of the JSPLIT msg partials.
__global__ __launch_bounds__(256) void mlp_kernel(
    const float* __restrict__ msgp,
    const float* __restrict__ W_fm, const float* __restrict__ b_fm,
    const float* __restrict__ W_c1, const float* __restrict__ b_c1,
    const float* __restrict__ W_p1, const float* __restrict__ b_p1,
    const float* __restrict__ W_c2, const float* __restrict__ b_c2,
    const float* __restrict__ W_p2, const float* __restrict__ b_p2,
    const float* __restrict__ W_c3, const float* __restrict__ b_c3,
    const float* __restrict__ W_h, const float* __restrict__ b_h,
    float* __restrict__ out) {
  const int i = blockIdx.x * blockDim.x + threadIdx.x;
  if (i >= N) return;

  float h0[8];
#pragma unroll
  for (int f = 0; f < 8; ++f) h0[f] = msgp[(size_t)i * 8 + f];
#pragma unroll
  for (int y = 1; y < JSPLIT; ++y)
#pragma unroll
    for (int f = 0; f < 8; ++f)
      h0[f] += msgp[((size_t)y * N + i) * 8 + f];

  float h1[16];
#pragma unroll
  for (int o = 0; o < 16; ++o) {
    float z = b_fm[o];
#pragma unroll
    for (int k = 0; k < 8; ++k) z += h0[k] * W_fm[k * 16 + o];
    h1[o] = tanhf(z);
  }
  float h2[16];
#pragma unroll
  for (int o = 0; o < 16; ++o) {
    float z = b_c1[o];
#pragma unroll
    for (int k = 0; k < 16; ++k) z += h1[k] * W_c1[k * 16 + o];
    h2[o] = tanhf(z);
  }
  float h3[12];
#pragma unroll
  for (int o = 0; o < 12; ++o) {
    float z = b_p1[o];
#pragma unroll
    for (int k = 0; k < 16; ++k) z += h2[k] * W_p1[k * 12 + o];
    h3[o] = tanhf(z);
  }
  float h4[8];
#pragma unroll
  for (int o = 0; o < 8; ++o) {
    float z = b_c2[o];
#pragma unroll
    for (int k = 0; k < 12; ++k) z += h3[k] * W_c2[k * 8 + o];
    h4[o] = tanhf(z);
  }
  float h5[4];
#pragma unroll
  for (int o = 0; o < 4; ++o) {
    float z = b_p2[o];
#pragma unroll
    for (int k = 0; k < 8; ++k) z += h4[k] * W_p2[k * 4 + o];
    h5[o] = tanhf(z);
  }
  float h6[4];
#pragma unroll
  for (int o = 0; o < 4; ++o) {
    float z = b_c3[o];
#pragma unroll
    for (int k = 0; k < 4; ++k) z += h5[k] * W_c3[k * 4 + o];
    h6[o] = tanhf(z);
  }
  float z = b_h[0];
#pragma unroll
  for (int k = 0; k < 4; ++k) z += h6[k] * W_h[k];
  out[i] = sigmoidf_(z);
}

extern "C" void kernel_launch(void* const* d_in, const int* in_sizes, int n_in,
                              void* d_out, int out_size, void* d_ws,
                              size_t ws_size, hipStream_t stream) {
  const float* A = (const float*)d_in[0];
  const float* X = (const float*)d_in[1];
  const float* W_fm = (const float*)d_in[2];
  const float* b_fm = (const float*)d_in[3];
  const float* W_c1 = (const float*)d_in[4];
  const float* b_c1 = (const float*)d_in[5];
  const float* W_p1 = (const float*)d_in[6];
  const float* b_p1 = (const float*)d_in[7];
  const float* W_c2 = (const float*)d_in[8];
  const float* b_c2 = (const float*)d_in[9];
  const float* W_p2 = (const float*)d_in[10];
  const float* b_p2 = (const float*)d_in[11];
  const float* W_c3 = (const float*)d_in[12];
  const float* b_c3 = (const float*)d_in[13];
  const float* W_h = (const float*)d_in[14];
  const float* b_h = (const float*)d_in[15];
  float* out = (float*)d_out;

  // Per-JSPLIT partial sums, (JSPLIT, N, 8) fp32 = 1 MiB. Every element is
  // written exactly once by a plain store -> no memset needed under the
  // 0xAA workspace poison.
  float* msgp = (float*)d_ws;

  dim3 grid(N / RPB, JSPLIT);
  msg_pass_kernel<<<grid, dim3(256), 0, stream>>>(A, X, msgp);

  mlp_kernel<<<dim3(N / 256), dim3(256), 0, stream>>>(
      msgp, W_fm, b_fm, W_c1, b_c1, W_p1, b_p1, W_c2, b_c2, W_p2, b_p2, W_c3,
      b_c3, W_h, b_h, out);
}

// Round 4
// 753.552 us; speedup vs baseline: 1.0156x; 1.0156x over previous
//
#include <hip/hip_runtime.h>
#include <math.h>

#define N 8192
#define F 8
#define RPW 2                 // rows per wave
#define WPB 4                 // waves per block
#define RPB (RPW * WPB)       // 8 rows per block
#define JSPLIT 4
#define JCHUNK (N / JSPLIT)   // 2048 columns per block
#define TJ 256                // j-tile staged in LDS per iteration
#define NIT (JCHUNK / TJ)     // 8 iterations
#define THRF 0.9f

// msg[i][f] = sum_j max(A[i][j], fid_adj[i][j]) * X[j][f]
// fid_adj = 1 iff (xn_i . xn_j)^2 >= 0.9 and i != j, xn = X/(||X||+1e-12).
// A ~ U[0,1) so max(a,1)==1 exactly -> adj = sel ? 1.0f : a.
//
// v5 = v4's structure with spill-proof codegen:
//  - NO lambdas / NO arrays passed by pointer (v4's 1GB scratch traffic,
//    VGPR_Count=40, came from SROA failing on lambda array params).
//    All pipeline state is statically-named float4 scalars via macros.
//  - LDS tile as float2 planes xP[4][TJ]: j-row read = 4x ds_read_b64 +
//    1x ds_read_b32, lane stride 8B -> 2 lanes/bank -> conflict-free.
//  - stage-side row swizzle (slot k*64+lane holds tile-row lane*4+k) so
//    A loads stay float4-coalesced and LDS reads stay stride-1.
//  - select test on raw X: (xi.X_j)^2 >= 0.9*||X_j||^2; diagonal repaired
//    post-reduction: v += (A[i][i]-1)*X[i][f]  (verified in v3/v4).
//  - plain stores to per-JSPLIT partials (poison-safe, no memset/atomics).
__global__ __launch_bounds__(256, 6) void msg_pass_kernel(
    const float* __restrict__ A, const float* __restrict__ X,
    float* __restrict__ msgp) {
  __shared__ float2 xP[2][4][TJ];  // plane p holds (X[:,2p], X[:,2p+1])
  __shared__ float tq[2][TJ];      // 0.9 * ||X_row||^2

  const int t = threadIdx.x;
  const int lane = t & 63;
  const int wave = t >> 6;
  const int i0 = blockIdx.x * RPB + wave * RPW;
  const int jbase = blockIdx.y * JCHUNK;
  const int srow = (lane << 2) | wave;  // stage-side source tile-row

  // Normalized xi rows (wave-uniform) -> SGPR broadcast.
  float xi0[F], xi1[F];
  {
    const float4* xp = (const float4*)(X + (size_t)i0 * F);
    const float4 lo = xp[0], hi = xp[1];
    const float ss = lo.x * lo.x + lo.y * lo.y + lo.z * lo.z + lo.w * lo.w +
                     hi.x * hi.x + hi.y * hi.y + hi.z * hi.z + hi.w * hi.w;
    const float inv = 1.0f / (sqrtf(ss) + 1e-12f);
    const float v[F] = {lo.x * inv, lo.y * inv, lo.z * inv, lo.w * inv,
                        hi.x * inv, hi.y * inv, hi.z * inv, hi.w * inv};
#pragma unroll
    for (int f = 0; f < F; ++f)
      xi0[f] = __int_as_float(
          __builtin_amdgcn_readfirstlane(__float_as_int(v[f])));
  }
  {
    const float4* xp = (const float4*)(X + (size_t)(i0 + 1) * F);
    const float4 lo = xp[0], hi = xp[1];
    const float ss = lo.x * lo.x + lo.y * lo.y + lo.z * lo.z + lo.w * lo.w +
                     hi.x * hi.x + hi.y * hi.y + hi.z * hi.z + hi.w * hi.w;
    const float inv = 1.0f / (sqrtf(ss) + 1e-12f);
    const float v[F] = {lo.x * inv, lo.y * inv, lo.z * inv, lo.w * inv,
                        hi.x * inv, hi.y * inv, hi.z * inv, hi.w * inv};
#pragma unroll
    for (int f = 0; f < F; ++f)
      xi1[f] = __int_as_float(
          __builtin_amdgcn_readfirstlane(__float_as_int(v[f])));
  }

  float acc0[F], acc1[F];
#pragma unroll
  for (int f = 0; f < F; ++f) {
    acc0[f] = 0.f;
    acc1[f] = 0.f;
  }

  const float* A0 = A + (size_t)i0 * N + jbase + (size_t)lane * 4;
  const float* A1 = A0 + N;
  const float* Xs = X + (size_t)(jbase + srow) * F;

#define LOADA(avA, avB, it_)                              \
  avA = *(const float4*)(A0 + (size_t)(it_) * TJ);        \
  avB = *(const float4*)(A1 + (size_t)(it_) * TJ)

#define LOADX(it_)                                                  \
  plo = ((const float4*)(Xs + (size_t)(it_) * TJ * F))[0];          \
  phi = ((const float4*)(Xs + (size_t)(it_) * TJ * F))[1]

#define STAGE(b_)                                                       \
  do {                                                                  \
    const float ss_ = plo.x * plo.x + plo.y * plo.y + plo.z * plo.z +   \
                      plo.w * plo.w + phi.x * phi.x + phi.y * phi.y +   \
                      phi.z * phi.z + phi.w * phi.w;                    \
    xP[b_][0][t] = make_float2(plo.x, plo.y);                           \
    xP[b_][1][t] = make_float2(plo.z, plo.w);                           \
    xP[b_][2][t] = make_float2(phi.x, phi.y);                           \
    xP[b_][3][t] = make_float2(phi.z, phi.w);                           \
    tq[b_][t] = THRF * ss_;                                             \
  } while (0)

#define KSTEP(b_, k_, avA, avB)                                         \
  do {                                                                  \
    const int slot = (k_)*64 + lane;                                    \
    const float2 x01 = xP[b_][0][slot];                                 \
    const float2 x23 = xP[b_][1][slot];                                 \
    const float2 x45 = xP[b_][2][slot];                                 \
    const float2 x67 = xP[b_][3][slot];                                 \
    const float tj = tq[b_][slot];                                      \
    float d0 = xi0[0] * x01.x;                                          \
    d0 = fmaf(xi0[1], x01.y, d0);                                       \
    d0 = fmaf(xi0[2], x23.x, d0);                                       \
    d0 = fmaf(xi0[3], x23.y, d0);                                       \
    d0 = fmaf(xi0[4], x45.x, d0);                                       \
    d0 = fmaf(xi0[5], x45.y, d0);                                       \
    d0 = fmaf(xi0[6], x67.x, d0);                                       \
    d0 = fmaf(xi0[7], x67.y, d0);                                       \
    float d1 = xi1[0] * x01.x;                                          \
    d1 = fmaf(xi1[1], x01.y, d1);                                       \
    d1 = fmaf(xi1[2], x23.x, d1);                                       \
    d1 = fmaf(xi1[3], x23.y, d1);                                       \
    d1 = fmaf(xi1[4], x45.x, d1);                                       \
    d1 = fmaf(xi1[5], x45.y, d1);                                       \
    d1 = fmaf(xi1[6], x67.x, d1);                                       \
    d1 = fmaf(xi1[7], x67.y, d1);                                       \
    const float aA = ((k_) == 0)   ? avA.x                              \
                     : ((k_) == 1) ? avA.y                              \
                     : ((k_) == 2) ? avA.z                              \
                                   : avA.w;                             \
    const float aB = ((k_) == 0)   ? avB.x                              \
                     : ((k_) == 1) ? avB.y                              \
                     : ((k_) == 2) ? avB.z                              \
                                   : avB.w;                             \
    const float c0 = (d0 * d0 >= tj) ? 1.0f : aA;                       \
    const float c1 = (d1 * d1 >= tj) ? 1.0f : aB;                       \
    acc0[0] = fmaf(c0, x01.x, acc0[0]);                                 \
    acc0[1] = fmaf(c0, x01.y, acc0[1]);                                 \
    acc0[2] = fmaf(c0, x23.x, acc0[2]);                                 \
    acc0[3] = fmaf(c0, x23.y, acc0[3]);                                 \
    acc0[4] = fmaf(c0, x45.x, acc0[4]);                                 \
    acc0[5] = fmaf(c0, x45.y, acc0[5]);                                 \
    acc0[6] = fmaf(c0, x67.x, acc0[6]);                                 \
    acc0[7] = fmaf(c0, x67.y, acc0[7]);                                 \
    acc1[0] = fmaf(c1, x01.x, acc1[0]);                                 \
    acc1[1] = fmaf(c1, x01.y, acc1[1]);                                 \
    acc1[2] = fmaf(c1, x23.x, acc1[2]);                                 \
    acc1[3] = fmaf(c1, x23.y, acc1[3]);                                 \
    acc1[4] = fmaf(c1, x45.x, acc1[4]);                                 \
    acc1[5] = fmaf(c1, x45.y, acc1[5]);                                 \
    acc1[6] = fmaf(c1, x67.x, acc1[6]);                                 \
    acc1[7] = fmaf(c1, x67.y, acc1[7]);                                 \
  } while (0)

#define COMPUTE(b_, avA, avB) \
  KSTEP(b_, 0, avA, avB);     \
  KSTEP(b_, 1, avA, avB);     \
  KSTEP(b_, 2, avA, avB);     \
  KSTEP(b_, 3, avA, avB)

  // Prologue: tile 0 resident in buf0 + av0*.
  float4 av00, av01, av10, av11, plo, phi;
  LOADA(av00, av01, 0);
  LOADX(0);
  STAGE(0);
  __syncthreads();

#pragma unroll 1
  for (int ith = 0; ith < NIT; ith += 2) {
    // even tile: compute buf0, prefetch+stage tile ith+1 -> buf1
    LOADA(av10, av11, ith + 1);
    LOADX(ith + 1);
    COMPUTE(0, av00, av01);
    STAGE(1);
    __syncthreads();
    // odd tile: compute buf1, prefetch+stage tile ith+2 -> buf0
    if (ith + 2 < NIT) {
      LOADA(av00, av01, ith + 2);
      LOADX(ith + 2);
    }
    COMPUTE(1, av10, av11);
    if (ith + 2 < NIT) STAGE(0);
    __syncthreads();
  }

  // Butterfly reduce; lane (r*8+f) owns that output. Diagonal term (added
  // with coef 1.0 in-loop) repaired here: += (A[i][i]-1)*X[i][f].
  const bool diagblk = ((unsigned)(i0 - jbase) < (unsigned)JCHUNK);
#pragma unroll
  for (int f = 0; f < F; ++f) {
    float v = acc0[f];
#pragma unroll
    for (int off = 1; off < 64; off <<= 1) v += __shfl_xor(v, off, 64);
    if (lane == f) {
      if (diagblk)
        v += (A[(size_t)i0 * N + i0] - 1.0f) * X[(size_t)i0 * F + f];
      msgp[((size_t)blockIdx.y * N + i0) * F + f] = v;
    }
  }
#pragma unroll
  for (int f = 0; f < F; ++f) {
    float v = acc1[f];
#pragma unroll
    for (int off = 1; off < 64; off <<= 1) v += __shfl_xor(v, off, 64);
    if (lane == F + f) {
      const int i1 = i0 + 1;
      if (diagblk)
        v += (A[(size_t)i1 * N + i1] - 1.0f) * X[(size_t)i1 * F + f];
      msgp[((size_t)blockIdx.y * N + i1) * F + f] = v;
    }
  }
}

__device__ __forceinline__ float sigmoidf_(float z) {
  return 1.0f / (1.0f + expf(-z));
}

// Per-node MLP chain. Weights are (fan_in, fan_out) row-major.
// h0 = sum of the JSPLIT msg partials.
__global__ __launch_bounds__(256) void mlp_kernel(
    const float* __restrict__ msgp,
    const float* __restrict__ W_fm, const float* __restrict__ b_fm,
    const float* __restrict__ W_c1, const float* __restrict__ b_c1,
    const float* __restrict__ W_p1, const float* __restrict__ b_p1,
    const float* __restrict__ W_c2, const float* __restrict__ b_c2,
    const float* __restrict__ W_p2, const float* __restrict__ b_p2,
    const float* __restrict__ W_c3, const float* __restrict__ b_c3,
    const float* __restrict__ W_h, const float* __restrict__ b_h,
    float* __restrict__ out) {
  const int i = blockIdx.x * blockDim.x + threadIdx.x;
  if (i >= N) return;

  float h0[8];
#pragma unroll
  for (int f = 0; f < 8; ++f) h0[f] = msgp[(size_t)i * 8 + f];
#pragma unroll
  for (int y = 1; y < JSPLIT; ++y)
#pragma unroll
    for (int f = 0; f < 8; ++f)
      h0[f] += msgp[((size_t)y * N + i) * 8 + f];

  float h1[16];
#pragma unroll
  for (int o = 0; o < 16; ++o) {
    float z = b_fm[o];
#pragma unroll
    for (int k = 0; k < 8; ++k) z += h0[k] * W_fm[k * 16 + o];
    h1[o] = tanhf(z);
  }
  float h2[16];
#pragma unroll
  for (int o = 0; o < 16; ++o) {
    float z = b_c1[o];
#pragma unroll
    for (int k = 0; k < 16; ++k) z += h1[k] * W_c1[k * 16 + o];
    h2[o] = tanhf(z);
  }
  float h3[12];
#pragma unroll
  for (int o = 0; o < 12; ++o) {
    float z = b_p1[o];
#pragma unroll
    for (int k = 0; k < 16; ++k) z += h2[k] * W_p1[k * 12 + o];
    h3[o] = tanhf(z);
  }
  float h4[8];
#pragma unroll
  for (int o = 0; o < 8; ++o) {
    float z = b_c2[o];
#pragma unroll
    for (int k = 0; k < 12; ++k) z += h3[k] * W_c2[k * 8 + o];
    h4[o] = tanhf(z);
  }
  float h5[4];
#pragma unroll
  for (int o = 0; o < 4; ++o) {
    float z = b_p2[o];
#pragma unroll
    for (int k = 0; k < 8; ++k) z += h4[k] * W_p2[k * 4 + o];
    h5[o] = tanhf(z);
  }
  float h6[4];
#pragma unroll
  for (int o = 0; o < 4; ++o) {
    float z = b_c3[o];
#pragma unroll
    for (int k = 0; k < 4; ++k) z += h5[k] * W_c3[k * 4 + o];
    h6[o] = tanhf(z);
  }
  float z = b_h[0];
#pragma unroll
  for (int k = 0; k < 4; ++k) z += h6[k] * W_h[k];
  out[i] = sigmoidf_(z);
}

extern "C" void kernel_launch(void* const* d_in, const int* in_sizes, int n_in,
                              void* d_out, int out_size, void* d_ws,
                              size_t ws_size, hipStream_t stream) {
  const float* A = (const float*)d_in[0];
  const float* X = (const float*)d_in[1];
  const float* W_fm = (const float*)d_in[2];
  const float* b_fm = (const float*)d_in[3];
  const float* W_c1 = (const float*)d_in[4];
  const float* b_c1 = (const float*)d_in[5];
  const float* W_p1 = (const float*)d_in[6];
  const float* b_p1 = (const float*)d_in[7];
  const float* W_c2 = (const float*)d_in[8];
  const float* b_c2 = (const float*)d_in[9];
  const float* W_p2 = (const float*)d_in[10];
  const float* b_p2 = (const float*)d_in[11];
  const float* W_c3 = (const float*)d_in[12];
  const float* b_c3 = (const float*)d_in[13];
  const float* W_h = (const float*)d_in[14];
  const float* b_h = (const float*)d_in[15];
  float* out = (float*)d_out;

  // Per-JSPLIT partial sums, (JSPLIT, N, 8) fp32 = 1 MiB. Every element is
  // written exactly once by a plain store -> no memset needed under the
  // 0xAA workspace poison.
  float* msgp = (float*)d_ws;

  dim3 grid(N / RPB, JSPLIT);
  msg_pass_kernel<<<grid, dim3(256), 0, stream>>>(A, X, msgp);

  mlp_kernel<<<dim3(N / 256), dim3(256), 0, stream>>>(
      msgp, W_fm, b_fm, W_c1, b_c1, W_p1, b_p1, W_c2, b_c2, W_p2, b_p2, W_c3,
      b_c3, W_h, b_h, out);
}

// Round 6
// 410.438 us; speedup vs baseline: 1.8646x; 1.8360x over previous
//
#include <hip/hip_runtime.h>
#include <math.h>

#define N 8192
#define F 8
#define RPW 2                 // rows per wave
#define WPB 4                 // waves per block
#define RPB (RPW * WPB)       // 8 rows per block
#define JSPLIT 4
#define JCHUNK (N / JSPLIT)   // 2048 columns per block
#define TJ 256                // j-tile staged in LDS per iteration
#define NIT (JCHUNK / TJ)     // 8 iterations
#define THRF 0.9f

// msg[i][f] = sum_j max(A[i][j], fid_adj[i][j]) * X[j][f]
// fid_adj = 1 iff (xn_i . xn_j)^2 >= 0.9 and i != j, xn = X/(||X||+1e-12).
// A ~ U[0,1) so max(a,1)==1 exactly -> adj = sel ? 1.0f : a.
//
// v6 = v5 with the REAL spill cause fixed: hipcc's gfx950 occupancy model
// caps arch-VGPRs at ~256/min_waves_per_EU. (256,6) -> cap 40 VGPR ->
// entire pipeline state spilled to scratch (v4/v5: WRITE_SIZE ~1 GB,
// VGPR_Count=40). (256,2) -> cap 128; state needs ~70 -> no spill, and
// the 512-reg unified HW file still co-schedules 6+ waves/SIMD at ~72.
//  - LDS tile as float2 planes xP[4][TJ]: lane stride 8B -> conflict-free.
//  - stage-side row swizzle (slot k*64+lane holds tile-row lane*4+k) so
//    A loads stay float4-coalesced and LDS reads stay stride-1.
//  - select test on raw X: (xi.X_j)^2 >= 0.9*||X_j||^2; diagonal repaired
//    post-reduction: v += (A[i][i]-1)*X[i][f]  (verified v3/v4/v5).
//  - plain stores to per-JSPLIT partials (poison-safe, no memset/atomics).
__global__ __launch_bounds__(256, 2) void msg_pass_kernel(
    const float* __restrict__ A, const float* __restrict__ X,
    float* __restrict__ msgp) {
  __shared__ float2 xP[2][4][TJ];  // plane p holds (X[:,2p], X[:,2p+1])
  __shared__ float tq[2][TJ];      // 0.9 * ||X_row||^2

  const int t = threadIdx.x;
  const int lane = t & 63;
  const int wave = t >> 6;
  const int i0 = blockIdx.x * RPB + wave * RPW;
  const int jbase = blockIdx.y * JCHUNK;
  const int srow = (lane << 2) | wave;  // stage-side source tile-row

  // Normalized xi rows (wave-uniform) -> SGPR broadcast.
  float xi0[F], xi1[F];
  {
    const float4* xp = (const float4*)(X + (size_t)i0 * F);
    const float4 lo = xp[0], hi = xp[1];
    const float ss = lo.x * lo.x + lo.y * lo.y + lo.z * lo.z + lo.w * lo.w +
                     hi.x * hi.x + hi.y * hi.y + hi.z * hi.z + hi.w * hi.w;
    const float inv = 1.0f / (sqrtf(ss) + 1e-12f);
    const float v[F] = {lo.x * inv, lo.y * inv, lo.z * inv, lo.w * inv,
                        hi.x * inv, hi.y * inv, hi.z * inv, hi.w * inv};
#pragma unroll
    for (int f = 0; f < F; ++f)
      xi0[f] = __int_as_float(
          __builtin_amdgcn_readfirstlane(__float_as_int(v[f])));
  }
  {
    const float4* xp = (const float4*)(X + (size_t)(i0 + 1) * F);
    const float4 lo = xp[0], hi = xp[1];
    const float ss = lo.x * lo.x + lo.y * lo.y + lo.z * lo.z + lo.w * lo.w +
                     hi.x * hi.x + hi.y * hi.y + hi.z * hi.z + hi.w * hi.w;
    const float inv = 1.0f / (sqrtf(ss) + 1e-12f);
    const float v[F] = {lo.x * inv, lo.y * inv, lo.z * inv, lo.w * inv,
                        hi.x * inv, hi.y * inv, hi.z * inv, hi.w * inv};
#pragma unroll
    for (int f = 0; f < F; ++f)
      xi1[f] = __int_as_float(
          __builtin_amdgcn_readfirstlane(__float_as_int(v[f])));
  }

  float acc0[F], acc1[F];
#pragma unroll
  for (int f = 0; f < F; ++f) {
    acc0[f] = 0.f;
    acc1[f] = 0.f;
  }

  const float* A0 = A + (size_t)i0 * N + jbase + (size_t)lane * 4;
  const float* A1 = A0 + N;
  const float* Xs = X + (size_t)(jbase + srow) * F;

#define LOADA(avA, avB, it_)                              \
  avA = *(const float4*)(A0 + (size_t)(it_) * TJ);        \
  avB = *(const float4*)(A1 + (size_t)(it_) * TJ)

#define LOADX(it_)                                                  \
  plo = ((const float4*)(Xs + (size_t)(it_) * TJ * F))[0];          \
  phi = ((const float4*)(Xs + (size_t)(it_) * TJ * F))[1]

#define STAGE(b_)                                                       \
  do {                                                                  \
    const float ss_ = plo.x * plo.x + plo.y * plo.y + plo.z * plo.z +   \
                      plo.w * plo.w + phi.x * phi.x + phi.y * phi.y +   \
                      phi.z * phi.z + phi.w * phi.w;                    \
    xP[b_][0][t] = make_float2(plo.x, plo.y);                           \
    xP[b_][1][t] = make_float2(plo.z, plo.w);                           \
    xP[b_][2][t] = make_float2(phi.x, phi.y);                           \
    xP[b_][3][t] = make_float2(phi.z, phi.w);                           \
    tq[b_][t] = THRF * ss_;                                             \
  } while (0)

#define KSTEP(b_, k_, avA, avB)                                         \
  do {                                                                  \
    const int slot = (k_)*64 + lane;                                    \
    const float2 x01 = xP[b_][0][slot];                                 \
    const float2 x23 = xP[b_][1][slot];                                 \
    const float2 x45 = xP[b_][2][slot];                                 \
    const float2 x67 = xP[b_][3][slot];                                 \
    const float tj = tq[b_][slot];                                      \
    float d0 = xi0[0] * x01.x;                                          \
    d0 = fmaf(xi0[1], x01.y, d0);                                       \
    d0 = fmaf(xi0[2], x23.x, d0);                                       \
    d0 = fmaf(xi0[3], x23.y, d0);                                       \
    d0 = fmaf(xi0[4], x45.x, d0);                                       \
    d0 = fmaf(xi0[5], x45.y, d0);                                       \
    d0 = fmaf(xi0[6], x67.x, d0);                                       \
    d0 = fmaf(xi0[7], x67.y, d0);                                       \
    float d1 = xi1[0] * x01.x;                                          \
    d1 = fmaf(xi1[1], x01.y, d1);                                       \
    d1 = fmaf(xi1[2], x23.x, d1);                                       \
    d1 = fmaf(xi1[3], x23.y, d1);                                       \
    d1 = fmaf(xi1[4], x45.x, d1);                                       \
    d1 = fmaf(xi1[5], x45.y, d1);                                       \
    d1 = fmaf(xi1[6], x67.x, d1);                                       \
    d1 = fmaf(xi1[7], x67.y, d1);                                       \
    const float aA = ((k_) == 0)   ? avA.x                              \
                     : ((k_) == 1) ? avA.y                              \
                     : ((k_) == 2) ? avA.z                              \
                                   : avA.w;                             \
    const float aB = ((k_) == 0)   ? avB.x                              \
                     : ((k_) == 1) ? avB.y                              \
                     : ((k_) == 2) ? avB.z                              \
                                   : avB.w;                             \
    const float c0 = (d0 * d0 >= tj) ? 1.0f : aA;                       \
    const float c1 = (d1 * d1 >= tj) ? 1.0f : aB;                       \
    acc0[0] = fmaf(c0, x01.x, acc0[0]);                                 \
    acc0[1] = fmaf(c0, x01.y, acc0[1]);                                 \
    acc0[2] = fmaf(c0, x23.x, acc0[2]);                                 \
    acc0[3] = fmaf(c0, x23.y, acc0[3]);                                 \
    acc0[4] = fmaf(c0, x45.x, acc0[4]);                                 \
    acc0[5] = fmaf(c0, x45.y, acc0[5]);                                 \
    acc0[6] = fmaf(c0, x67.x, acc0[6]);                                 \
    acc0[7] = fmaf(c0, x67.y, acc0[7]);                                 \
    acc1[0] = fmaf(c1, x01.x, acc1[0]);                                 \
    acc1[1] = fmaf(c1, x01.y, acc1[1]);                                 \
    acc1[2] = fmaf(c1, x23.x, acc1[2]);                                 \
    acc1[3] = fmaf(c1, x23.y, acc1[3]);                                 \
    acc1[4] = fmaf(c1, x45.x, acc1[4]);                                 \
    acc1[5] = fmaf(c1, x45.y, acc1[5]);                                 \
    acc1[6] = fmaf(c1, x67.x, acc1[6]);                                 \
    acc1[7] = fmaf(c1, x67.y, acc1[7]);                                 \
  } while (0)

#define COMPUTE(b_, avA, avB) \
  KSTEP(b_, 0, avA, avB);     \
  KSTEP(b_, 1, avA, avB);     \
  KSTEP(b_, 2, avA, avB);     \
  KSTEP(b_, 3, avA, avB)

  // Prologue: tile 0 resident in buf0 + av0*.
  float4 av00, av01, av10, av11, plo, phi;
  LOADA(av00, av01, 0);
  LOADX(0);
  STAGE(0);
  __syncthreads();

#pragma unroll 1
  for (int ith = 0; ith < NIT; ith += 2) {
    // even tile: compute buf0, prefetch+stage tile ith+1 -> buf1
    LOADA(av10, av11, ith + 1);
    LOADX(ith + 1);
    COMPUTE(0, av00, av01);
    STAGE(1);
    __syncthreads();
    // odd tile: compute buf1, prefetch+stage ith+2 -> buf0
    if (ith + 2 < NIT) {
      LOADA(av00, av01, ith + 2);
      LOADX(ith + 2);
    }
    COMPUTE(1, av10, av11);
    if (ith + 2 < NIT) STAGE(0);
    __syncthreads();
  }

  // Butterfly reduce; lane (r*8+f) owns that output. Diagonal term (added
  // with coef 1.0 in-loop) repaired here: += (A[i][i]-1)*X[i][f].
  const bool diagblk = ((unsigned)(i0 - jbase) < (unsigned)JCHUNK);
#pragma unroll
  for (int f = 0; f < F; ++f) {
    float v = acc0[f];
#pragma unroll
    for (int off = 1; off < 64; off <<= 1) v += __shfl_xor(v, off, 64);
    if (lane == f) {
      if (diagblk)
        v += (A[(size_t)i0 * N + i0] - 1.0f) * X[(size_t)i0 * F + f];
      msgp[((size_t)blockIdx.y * N + i0) * F + f] = v;
    }
  }
#pragma unroll
  for (int f = 0; f < F; ++f) {
    float v = acc1[f];
#pragma unroll
    for (int off = 1; off < 64; off <<= 1) v += __shfl_xor(v, off, 64);
    if (lane == F + f) {
      const int i1 = i0 + 1;
      if (diagblk)
        v += (A[(size_t)i1 * N + i1] - 1.0f) * X[(size_t)i1 * F + f];
      msgp[((size_t)blockIdx.y * N + i1) * F + f] = v;
    }
  }
}

__device__ __forceinline__ float sigmoidf_(float z) {
  return 1.0f / (1.0f + expf(-z));
}

// Per-node MLP chain. Weights are (fan_in, fan_out) row-major.
// h0 = sum of the JSPLIT msg partials.
__global__ __launch_bounds__(256) void mlp_kernel(
    const float* __restrict__ msgp,
    const float* __restrict__ W_fm, const float* __restrict__ b_fm,
    const float* __restrict__ W_c1, const float* __restrict__ b_c1,
    const float* __restrict__ W_p1, const float* __restrict__ b_p1,
    const float* __restrict__ W_c2, const float* __restrict__ b_c2,
    const float* __restrict__ W_p2, const float* __restrict__ b_p2,
    const float* __restrict__ W_c3, const float* __restrict__ b_c3,
    const float* __restrict__ W_h, const float* __restrict__ b_h,
    float* __restrict__ out) {
  const int i = blockIdx.x * blockDim.x + threadIdx.x;
  if (i >= N) return;

  float h0[8];
#pragma unroll
  for (int f = 0; f < 8; ++f) h0[f] = msgp[(size_t)i * 8 + f];
#pragma unroll
  for (int y = 1; y < JSPLIT; ++y)
#pragma unroll
    for (int f = 0; f < 8; ++f)
      h0[f] += msgp[((size_t)y * N + i) * 8 + f];

  float h1[16];
#pragma unroll
  for (int o = 0; o < 16; ++o) {
    float z = b_fm[o];
#pragma unroll
    for (int k = 0; k < 8; ++k) z += h0[k] * W_fm[k * 16 + o];
    h1[o] = tanhf(z);
  }
  float h2[16];
#pragma unroll
  for (int o = 0; o < 16; ++o) {
    float z = b_c1[o];
#pragma unroll
    for (int k = 0; k < 16; ++k) z += h1[k] * W_c1[k * 16 + o];
    h2[o] = tanhf(z);
  }
  float h3[12];
#pragma unroll
  for (int o = 0; o < 12; ++o) {
    float z = b_p1[o];
#pragma unroll
    for (int k = 0; k < 16; ++k) z += h2[k] * W_p1[k * 12 + o];
    h3[o] = tanhf(z);
  }
  float h4[8];
#pragma unroll
  for (int o = 0; o < 8; ++o) {
    float z = b_c2[o];
#pragma unroll
    for (int k = 0; k < 12; ++k) z += h3[k] * W_c2[k * 8 + o];
    h4[o] = tanhf(z);
  }
  float h5[4];
#pragma unroll
  for (int o = 0; o < 4; ++o) {
    float z = b_p2[o];
#pragma unroll
    for (int k = 0; k < 8; ++k) z += h4[k] * W_p2[k * 4 + o];
    h5[o] = tanhf(z);
  }
  float h6[4];
#pragma unroll
  for (int o = 0; o < 4; ++o) {
    float z = b_c3[o];
#pragma unroll
    for (int k = 0; k < 4; ++k) z += h5[k] * W_c3[k * 4 + o];
    h6[o] = tanhf(z);
  }
  float z = b_h[0];
#pragma unroll
  for (int k = 0; k < 4; ++k) z += h6[k] * W_h[k];
  out[i] = sigmoidf_(z);
}

extern "C" void kernel_launch(void* const* d_in, const int* in_sizes, int n_in,
                              void* d_out, int out_size, void* d_ws,
                              size_t ws_size, hipStream_t stream) {
  const float* A = (const float*)d_in[0];
  const float* X = (const float*)d_in[1];
  const float* W_fm = (const float*)d_in[2];
  const float* b_fm = (const float*)d_in[3];
  const float* W_c1 = (const float*)d_in[4];
  const float* b_c1 = (const float*)d_in[5];
  const float* W_p1 = (const float*)d_in[6];
  const float* b_p1 = (const float*)d_in[7];
  const float* W_c2 = (const float*)d_in[8];
  const float* b_c2 = (const float*)d_in[9];
  const float* W_p2 = (const float*)d_in[10];
  const float* b_p2 = (const float*)d_in[11];
  const float* W_c3 = (const float*)d_in[12];
  const float* b_c3 = (const float*)d_in[13];
  const float* W_h = (const float*)d_in[14];
  const float* b_h = (const float*)d_in[15];
  float* out = (float*)d_out;

  // Per-JSPLIT partial sums, (JSPLIT, N, 8) fp32 = 1 MiB. Every element is
  // written exactly once by a plain store -> no memset needed under the
  // 0xAA workspace poison.
  float* msgp = (float*)d_ws;

  dim3 grid(N / RPB, JSPLIT);
  msg_pass_kernel<<<grid, dim3(256), 0, stream>>>(A, X, msgp);

  mlp_kernel<<<dim3(N / 256), dim3(256), 0, stream>>>(
      msgp, W_fm, b_fm, W_c1, b_c1, W_p1, b_p1, W_c2, b_c2, W_p2, b_p2, W_c3,
      b_c3, W_h, b_h, out);
}